// Round 1
// baseline (973.400 us; speedup 1.0000x reference)
//
#include <hip/hip_runtime.h>
#include <hip/hip_bf16.h>

#define E_  8
#define T_  4096
#define DH_ 2048
#define DI_ 5632
#define R_  128
#define TILE_ 32
#define NT_ 136                 // T/32 + E  (worst-case padded tiles)
#define TPMAX_ (NT_*TILE_)      // 4352

__device__ __forceinline__ int tile_expert(int s0, const int* off) {
  int e = 0;
#pragma unroll
  for (int q = 1; q < E_; q++) if (s0 >= off[q]) e = q;
  return e;
}

__global__ void k_count(const int* __restrict__ idx, int* __restrict__ cnt) {
  int t = blockIdx.x * 256 + threadIdx.x;
  if (t < T_) atomicAdd(&cnt[idx[t]], 1);
}

__global__ void k_offsets(const int* __restrict__ cnt, int* __restrict__ off,
                          int* __restrict__ cur) {
  if (threadIdx.x == 0) {
    int a = 0;
    for (int e = 0; e < E_; e++) {
      off[e] = a; cur[e] = a;
      a += ((cnt[e] + TILE_ - 1) / TILE_) * TILE_;
    }
    off[E_] = a;
  }
}

__global__ void k_scatter(const int* __restrict__ idx, int* __restrict__ cur,
                          int* __restrict__ tok) {
  int t = blockIdx.x * 256 + threadIdx.x;
  if (t < T_) {
    int p = atomicAdd(&cur[idx[t]], 1);
    tok[p] = t;
  }
}

// Stage 1: H = C @ (A[e] @ x)   for gate (blockIdx.y=0) and up (blockIdx.y=1)
__global__ __launch_bounds__(256) void k_stage1(
    const float* __restrict__ x,
    const float* __restrict__ gA, const float* __restrict__ gC,
    const float* __restrict__ uA, const float* __restrict__ uC,
    const int* __restrict__ off, const int* __restrict__ tok,
    float* __restrict__ Hg, float* __restrict__ Hu)
{
  const int s0 = blockIdx.x * TILE_;
  if (s0 >= off[E_]) return;
  const int e = tile_expert(s0, off);
  const float* A = (blockIdx.y ? uA : gA) + (size_t)e * R_ * DH_;
  const float* C = blockIdx.y ? uC : gC;
  float* H = blockIdx.y ? Hu : Hg;

  __shared__ float xs[64][TILE_];   // [k][g]
  __shared__ float As[64][132];     // [k][r]

  const int tid = threadIdx.x;
  const int gb = (tid >> 5) * 4;    // 8 g-groups * 4
  const int rb = (tid & 31) * 4;    // 32 r-groups * 4

  const int lg = tid >> 3;
  const int lk = (tid & 7) * 8;
  const int t_load = tok[s0 + lg];
  const float* xrow = (t_load >= 0) ? x + (size_t)t_load * DH_ : nullptr;

  const int lr = tid >> 1;
  const int lkh = (tid & 1) * 32;
  const float* arow = A + (size_t)lr * DH_ + lkh;

  float acc[4][4] = {};

  for (int k0 = 0; k0 < DH_; k0 += 64) {
    float4 v0 = make_float4(0.f, 0.f, 0.f, 0.f), v1 = v0;
    if (xrow) {
      v0 = *(const float4*)(xrow + k0 + lk);
      v1 = *(const float4*)(xrow + k0 + lk + 4);
    }
    xs[lk + 0][lg] = v0.x; xs[lk + 1][lg] = v0.y;
    xs[lk + 2][lg] = v0.z; xs[lk + 3][lg] = v0.w;
    xs[lk + 4][lg] = v1.x; xs[lk + 5][lg] = v1.y;
    xs[lk + 6][lg] = v1.z; xs[lk + 7][lg] = v1.w;
#pragma unroll
    for (int q = 0; q < 8; q++) {
      float4 v = *(const float4*)(arow + k0 + q * 4);
      As[lkh + q * 4 + 0][lr] = v.x; As[lkh + q * 4 + 1][lr] = v.y;
      As[lkh + q * 4 + 2][lr] = v.z; As[lkh + q * 4 + 3][lr] = v.w;
    }
    __syncthreads();
#pragma unroll 8
    for (int k = 0; k < 64; k++) {
      float4 xv = *(const float4*)&xs[k][gb];
      float4 av = *(const float4*)&As[k][rb];
      const float* xp = (const float*)&xv;
      const float* ap = (const float*)&av;
#pragma unroll
      for (int gi = 0; gi < 4; gi++)
#pragma unroll
        for (int ri = 0; ri < 4; ri++)
          acc[gi][ri] += xp[gi] * ap[ri];
    }
    __syncthreads();
  }

  // C-apply epilogue: reuse As as h1s (rows 0..31) + CT (rows 32..63)
  float (*h1s)[132] = (float(*)[132])&As[0][0];
  float (*CT)[132]  = (float(*)[132])&As[32][0];
#pragma unroll
  for (int gi = 0; gi < 4; gi++)
#pragma unroll
    for (int ri = 0; ri < 4; ri++)
      h1s[gb + gi][rb + ri] = acc[gi][ri];

  float acc2[4][4] = {};
  const int ls = tid >> 1;
  const int lrh2 = (tid & 1) * 16;
  for (int rc = 0; rc < 4; rc++) {
    __syncthreads();
#pragma unroll
    for (int q = 0; q < 4; q++) {
      float4 v = *(const float4*)(C + ls * R_ + rc * 32 + lrh2 + q * 4);
      CT[lrh2 + q * 4 + 0][ls] = v.x; CT[lrh2 + q * 4 + 1][ls] = v.y;
      CT[lrh2 + q * 4 + 2][ls] = v.z; CT[lrh2 + q * 4 + 3][ls] = v.w;
    }
    __syncthreads();
#pragma unroll 8
    for (int r = 0; r < 32; r++) {
      float4 cv = *(const float4*)&CT[r][rb];
      const float* cp = (const float*)&cv;
      float hv[4];
#pragma unroll
      for (int gi = 0; gi < 4; gi++) hv[gi] = h1s[gb + gi][rc * 32 + r];
#pragma unroll
      for (int gi = 0; gi < 4; gi++)
#pragma unroll
        for (int si = 0; si < 4; si++)
          acc2[gi][si] += hv[gi] * cp[si];
    }
  }
#pragma unroll
  for (int gi = 0; gi < 4; gi++) {
    float4 o;
    o.x = acc2[gi][0]; o.y = acc2[gi][1]; o.z = acc2[gi][2]; o.w = acc2[gi][3];
    *(float4*)&H[(size_t)(s0 + gb + gi) * R_ + rb] = o;
  }
}

// Stage 2: G = Hg@Bg^T, U = Hu@Bu^T, Z = silu(G)*U, Hd1 += Z@Ad^T (per DI chunk)
__global__ __launch_bounds__(256) void k_stage2(
    const float* __restrict__ Hg, const float* __restrict__ Hu,
    const float* __restrict__ gBw, const float* __restrict__ uBw,
    const float* __restrict__ dA,
    const int* __restrict__ off, float* __restrict__ Hd1)
{
  const int s0 = blockIdx.x * TILE_;
  if (s0 >= off[E_]) return;
  const int e = tile_expert(s0, off);
  const int i0 = blockIdx.y * 512;
  const float* Bg = gBw + (size_t)e * DI_ * R_;
  const float* Bu = uBw + (size_t)e * DI_ * R_;
  const float* Ad = dA + (size_t)e * R_ * DI_;

  __shared__ float HgT[64][TILE_];
  __shared__ float HuT[64][TILE_];
  __shared__ float BgT[64][TILE_];
  __shared__ float BuT[64][TILE_];
  __shared__ float ZT[32][36];
  __shared__ float AdT[32][128];

  const int tid = threadIdx.x;
  const int g2 = (tid & 15) * 2;    // phase A: 16 g-groups * 2
  const int i2 = (tid >> 4) * 2;    //          16 i-groups * 2
  const int gB4 = (tid >> 5) * 4;   // phase B: 8 g-groups * 4
  const int rB4 = (tid & 31) * 4;   //          32 r-groups * 4
  const int lrow = tid >> 3;        // 0..31
  const int lk = (tid & 7) * 8;
  const int lr = tid >> 1;          // 0..127
  const int lih = (tid & 1) * 16;

  float acch[4][4] = {};

  for (int sc = 0; sc < 16; sc++) {
    const int ib = i0 + sc * 32;
    float ag[2][2] = {};
    float au[2][2] = {};
    for (int kc = 0; kc < 2; kc++) {
      {
        const float* hgp = Hg + (size_t)(s0 + lrow) * R_ + kc * 64 + lk;
        const float* hup = Hu + (size_t)(s0 + lrow) * R_ + kc * 64 + lk;
        const float* bgp = Bg + (size_t)(ib + lrow) * R_ + kc * 64 + lk;
        const float* bup = Bu + (size_t)(ib + lrow) * R_ + kc * 64 + lk;
        float4 a0 = *(const float4*)hgp, a1 = *(const float4*)(hgp + 4);
        float4 b0 = *(const float4*)hup, b1 = *(const float4*)(hup + 4);
        float4 c0 = *(const float4*)bgp, c1 = *(const float4*)(bgp + 4);
        float4 d0 = *(const float4*)bup, d1 = *(const float4*)(bup + 4);
        HgT[lk + 0][lrow] = a0.x; HgT[lk + 1][lrow] = a0.y; HgT[lk + 2][lrow] = a0.z; HgT[lk + 3][lrow] = a0.w;
        HgT[lk + 4][lrow] = a1.x; HgT[lk + 5][lrow] = a1.y; HgT[lk + 6][lrow] = a1.z; HgT[lk + 7][lrow] = a1.w;
        HuT[lk + 0][lrow] = b0.x; HuT[lk + 1][lrow] = b0.y; HuT[lk + 2][lrow] = b0.z; HuT[lk + 3][lrow] = b0.w;
        HuT[lk + 4][lrow] = b1.x; HuT[lk + 5][lrow] = b1.y; HuT[lk + 6][lrow] = b1.z; HuT[lk + 7][lrow] = b1.w;
        BgT[lk + 0][lrow] = c0.x; BgT[lk + 1][lrow] = c0.y; BgT[lk + 2][lrow] = c0.z; BgT[lk + 3][lrow] = c0.w;
        BgT[lk + 4][lrow] = c1.x; BgT[lk + 5][lrow] = c1.y; BgT[lk + 6][lrow] = c1.z; BgT[lk + 7][lrow] = c1.w;
        BuT[lk + 0][lrow] = d0.x; BuT[lk + 1][lrow] = d0.y; BuT[lk + 2][lrow] = d0.z; BuT[lk + 3][lrow] = d0.w;
        BuT[lk + 4][lrow] = d1.x; BuT[lk + 5][lrow] = d1.y; BuT[lk + 6][lrow] = d1.z; BuT[lk + 7][lrow] = d1.w;
      }
      __syncthreads();
#pragma unroll 8
      for (int k = 0; k < 64; k++) {
        float2 hg = *(const float2*)&HgT[k][g2];
        float2 hu = *(const float2*)&HuT[k][g2];
        float2 bg = *(const float2*)&BgT[k][i2];
        float2 bu = *(const float2*)&BuT[k][i2];
        ag[0][0] += hg.x * bg.x; ag[0][1] += hg.x * bg.y;
        ag[1][0] += hg.y * bg.x; ag[1][1] += hg.y * bg.y;
        au[0][0] += hu.x * bu.x; au[0][1] += hu.x * bu.y;
        au[1][0] += hu.y * bu.x; au[1][1] += hu.y * bu.y;
      }
      __syncthreads();
    }
    // silu(G)*U -> ZT  (transposed [i][g])
#pragma unroll
    for (int gi = 0; gi < 2; gi++)
#pragma unroll
      for (int ii = 0; ii < 2; ii++) {
        float gv = ag[gi][ii];
        float sv = gv / (1.0f + __expf(-gv));
        ZT[i2 + ii][g2 + gi] = sv * au[gi][ii];
      }
    // AdT load [i][r]
    {
      const float* adp = Ad + (size_t)lr * DI_ + ib + lih;
#pragma unroll
      for (int q = 0; q < 4; q++) {
        float4 v = *(const float4*)(adp + q * 4);
        AdT[lih + q * 4 + 0][lr] = v.x; AdT[lih + q * 4 + 1][lr] = v.y;
        AdT[lih + q * 4 + 2][lr] = v.z; AdT[lih + q * 4 + 3][lr] = v.w;
      }
    }
    __syncthreads();
    // phase B: acch[g][r] += Z[g][i] * Ad[r][i]
#pragma unroll 4
    for (int i = 0; i < 32; i++) {
      float4 zv = *(const float4*)&ZT[i][gB4];
      float4 av = *(const float4*)&AdT[i][rB4];
      const float* zp = (const float*)&zv;
      const float* ap = (const float*)&av;
#pragma unroll
      for (int gi = 0; gi < 4; gi++)
#pragma unroll
        for (int ri = 0; ri < 4; ri++)
          acch[gi][ri] += zp[gi] * ap[ri];
    }
    __syncthreads();
  }
#pragma unroll
  for (int gi = 0; gi < 4; gi++)
#pragma unroll
    for (int ri = 0; ri < 4; ri++)
      atomicAdd(&Hd1[(size_t)(s0 + gB4 + gi) * R_ + rB4 + ri], acch[gi][ri]);
}

// Hd2 = Cd @ Hd1 (per token row)
__global__ __launch_bounds__(256) void k_applyCd(
    const float* __restrict__ Hd1, const float* __restrict__ dC,
    const int* __restrict__ off, float* __restrict__ Hd2)
{
  const int s0 = blockIdx.x * TILE_;
  if (s0 >= off[E_]) return;
  __shared__ float h1s[TILE_][132];
  __shared__ float CT[32][132];
  const int tid = threadIdx.x;
  const int lg = tid >> 3, lq = (tid & 7) * 16;
#pragma unroll
  for (int q = 0; q < 4; q++) {
    float4 v = *(const float4*)(Hd1 + (size_t)(s0 + lg) * R_ + lq + q * 4);
    *(float4*)&h1s[lg][lq + q * 4] = v;
  }
  const int gb = (tid >> 5) * 4, sb = (tid & 31) * 4;
  const int ls = tid >> 1, lrh = (tid & 1) * 16;
  float acc[4][4] = {};
  for (int rc = 0; rc < 4; rc++) {
    __syncthreads();
#pragma unroll
    for (int q = 0; q < 4; q++) {
      float4 v = *(const float4*)(dC + ls * R_ + rc * 32 + lrh + q * 4);
      CT[lrh + q * 4 + 0][ls] = v.x; CT[lrh + q * 4 + 1][ls] = v.y;
      CT[lrh + q * 4 + 2][ls] = v.z; CT[lrh + q * 4 + 3][ls] = v.w;
    }
    __syncthreads();
#pragma unroll 8
    for (int r = 0; r < 32; r++) {
      float4 cv = *(const float4*)&CT[r][sb];
      const float* cp = (const float*)&cv;
      float hv[4];
#pragma unroll
      for (int gi = 0; gi < 4; gi++) hv[gi] = h1s[gb + gi][rc * 32 + r];
#pragma unroll
      for (int gi = 0; gi < 4; gi++)
#pragma unroll
        for (int si = 0; si < 4; si++)
          acc[gi][si] += hv[gi] * cp[si];
    }
  }
#pragma unroll
  for (int gi = 0; gi < 4; gi++) {
    float4 o;
    o.x = acc[gi][0]; o.y = acc[gi][1]; o.z = acc[gi][2]; o.w = acc[gi][3];
    *(float4*)&Hd2[(size_t)(s0 + gb + gi) * R_ + sb] = o;
  }
}

// Stage 3: out[t, d] = Hd2[g,:] @ Bd[e,d,:] + bias[e,d]
__global__ __launch_bounds__(256) void k_stage3(
    const float* __restrict__ Hd2, const float* __restrict__ dBw,
    const float* __restrict__ dbias,
    const int* __restrict__ off, const int* __restrict__ tok,
    float* __restrict__ out)
{
  const int s0 = blockIdx.x * TILE_;
  if (s0 >= off[E_]) return;
  const int e = tile_expert(s0, off);
  const int d0 = blockIdx.y * 64;
  const float* Bd = dBw + (size_t)e * DH_ * R_;

  __shared__ float HdT[128][TILE_];
  __shared__ float BdT[128][68];

  const int tid = threadIdx.x;
  {
    const int lg = tid >> 3, lq = (tid & 7) * 16;
    const float* hp = Hd2 + (size_t)(s0 + lg) * R_ + lq;
#pragma unroll
    for (int q = 0; q < 4; q++) {
      float4 v = *(const float4*)(hp + q * 4);
      HdT[lq + q * 4 + 0][lg] = v.x; HdT[lq + q * 4 + 1][lg] = v.y;
      HdT[lq + q * 4 + 2][lg] = v.z; HdT[lq + q * 4 + 3][lg] = v.w;
    }
    const int ld = tid >> 2, lq2 = (tid & 3) * 32;
    const float* bp = Bd + (size_t)(d0 + ld) * R_ + lq2;
#pragma unroll
    for (int q = 0; q < 8; q++) {
      float4 v = *(const float4*)(bp + q * 4);
      BdT[lq2 + q * 4 + 0][ld] = v.x; BdT[lq2 + q * 4 + 1][ld] = v.y;
      BdT[lq2 + q * 4 + 2][ld] = v.z; BdT[lq2 + q * 4 + 3][ld] = v.w;
    }
  }
  __syncthreads();
  const int g2 = (tid & 15) * 2;
  const int d4 = (tid >> 4) * 4;
  float acc[2][4] = {};
#pragma unroll 8
  for (int k = 0; k < 128; k++) {
    float2 hv = *(const float2*)&HdT[k][g2];
    float4 bv = *(const float4*)&BdT[k][d4];
    const float* bp = (const float*)&bv;
#pragma unroll
    for (int di = 0; di < 4; di++) {
      acc[0][di] += hv.x * bp[di];
      acc[1][di] += hv.y * bp[di];
    }
  }
  float4 bias4 = *(const float4*)(dbias + (size_t)e * DH_ + d0 + d4);
  const float* bb = (const float*)&bias4;
#pragma unroll
  for (int gi = 0; gi < 2; gi++) {
    int t = tok[s0 + g2 + gi];
    if (t >= 0) {
      float4 o;
      o.x = acc[gi][0] + bb[0]; o.y = acc[gi][1] + bb[1];
      o.z = acc[gi][2] + bb[2]; o.w = acc[gi][3] + bb[3];
      *(float4*)&out[(size_t)t * DH_ + d0 + d4] = o;
    }
  }
}

extern "C" void kernel_launch(void* const* d_in, const int* in_sizes, int n_in,
                              void* d_out, int out_size, void* d_ws, size_t ws_size,
                              hipStream_t stream)
{
  (void)in_sizes; (void)n_in; (void)out_size; (void)ws_size;
  const float* x     = (const float*)d_in[0];
  const int*   idx   = (const int*)d_in[1];
  const float* gA    = (const float*)d_in[2];
  const float* gC    = (const float*)d_in[3];
  const float* gBw   = (const float*)d_in[4];
  const float* uA    = (const float*)d_in[5];
  const float* uC    = (const float*)d_in[6];
  const float* uBw   = (const float*)d_in[7];
  const float* dA    = (const float*)d_in[8];
  const float* dC    = (const float*)d_in[9];
  const float* dBw   = (const float*)d_in[10];
  const float* dbias = (const float*)d_in[11];
  float* out = (float*)d_out;

  int* cnt = (int*)d_ws;            // 8
  int* cur = cnt + 8;               // 8
  int* off = cnt + 16;              // 9
  int* tok = (int*)((char*)d_ws + 512);
  float* Hg  = (float*)((char*)d_ws + 32768);
  float* Hu  = Hg  + (size_t)TPMAX_ * R_;
  float* Hd1 = Hu  + (size_t)TPMAX_ * R_;
  float* Hd2 = Hd1 + (size_t)TPMAX_ * R_;   // total ws use ~8.6 MB

  hipMemsetAsync(d_ws, 0, 128, stream);
  hipMemsetAsync(tok, 0xFF, TPMAX_ * sizeof(int), stream);
  hipMemsetAsync(Hd1, 0, (size_t)TPMAX_ * R_ * sizeof(float), stream);

  k_count  <<<dim3(T_ / 256), 256, 0, stream>>>(idx, cnt);
  k_offsets<<<1, 64, 0, stream>>>(cnt, off, cur);
  k_scatter<<<dim3(T_ / 256), 256, 0, stream>>>(idx, cur, tok);
  k_stage1 <<<dim3(NT_, 2), 256, 0, stream>>>(x, gA, gC, uA, uC, off, tok, Hg, Hu);
  k_stage2 <<<dim3(NT_, 11), 256, 0, stream>>>(Hg, Hu, gBw, uBw, dA, off, Hd1);
  k_applyCd<<<dim3(NT_), 256, 0, stream>>>(Hd1, dC, off, Hd2);
  k_stage3 <<<dim3(NT_, 32), 256, 0, stream>>>(Hd2, dBw, dbias, off, tok, out);
}

// Round 2
// 444.683 us; speedup vs baseline: 2.1890x; 2.1890x over previous
//
#include <hip/hip_runtime.h>
#include <hip/hip_bf16.h>

#define E_  8
#define T_  4096
#define DH_ 2048
#define DI_ 5632
#define R_  128
#define TILE_ 32
#define NT_ 136                 // T/32 + E  (worst-case padded tiles)
#define TPMAX_ (NT_*TILE_)      // 4352

typedef short bf16x8 __attribute__((ext_vector_type(8)));
typedef short bf16x4 __attribute__((ext_vector_type(4)));
typedef float f32x4 __attribute__((ext_vector_type(4)));

__device__ __forceinline__ unsigned short f2bf(float f) {
  union { float f; unsigned u; } v; v.f = f;
  return (unsigned short)((v.u + 0x7fffu + ((v.u >> 16) & 1u)) >> 16);
}

__device__ __forceinline__ bf16x8 cvt8(float4 a, float4 b) {
  bf16x8 o;
  o[0] = (short)f2bf(a.x); o[1] = (short)f2bf(a.y);
  o[2] = (short)f2bf(a.z); o[3] = (short)f2bf(a.w);
  o[4] = (short)f2bf(b.x); o[5] = (short)f2bf(b.y);
  o[6] = (short)f2bf(b.z); o[7] = (short)f2bf(b.w);
  return o;
}

__device__ __forceinline__ int tile_expert(int s0, const int* off) {
  int e = 0;
#pragma unroll
  for (int q = 1; q < E_; q++) if (s0 >= off[q]) e = q;
  return e;
}

__global__ void k_count(const int* __restrict__ idx, int* __restrict__ cnt) {
  int t = blockIdx.x * 256 + threadIdx.x;
  if (t < T_) atomicAdd(&cnt[idx[t]], 1);
}

__global__ void k_offsets(const int* __restrict__ cnt, int* __restrict__ off,
                          int* __restrict__ cur) {
  if (threadIdx.x == 0) {
    int a = 0;
    for (int e = 0; e < E_; e++) {
      off[e] = a; cur[e] = a;
      a += ((cnt[e] + TILE_ - 1) / TILE_) * TILE_;
    }
    off[E_] = a;
  }
}

__global__ void k_scatter(const int* __restrict__ idx, int* __restrict__ cur,
                          int* __restrict__ tok) {
  int t = blockIdx.x * 256 + threadIdx.x;
  if (t < T_) {
    int p = atomicAdd(&cur[idx[t]], 1);
    tok[p] = t;
  }
}

// Convert weights fp32 -> bf16 (pure dtype cast, layouts preserved)
__global__ __launch_bounds__(256) void k_cvt(
    const float* __restrict__ gA, const float* __restrict__ uA,
    const float* __restrict__ gB, const float* __restrict__ uB,
    const float* __restrict__ dA,
    const float* __restrict__ gC, const float* __restrict__ uC,
    short* __restrict__ gAb, short* __restrict__ uAb,
    short* __restrict__ gBb, short* __restrict__ uBb,
    short* __restrict__ dAb,
    short* __restrict__ gCb, short* __restrict__ uCb)
{
  long i = (long)(blockIdx.x * 256 + threadIdx.x) * 4;
  const float* s; short* d;
  if      (i <  4194304) { if (i < 2097152) { s = gA; d = gAb; } else { s = uA; d = uAb; i -= 2097152; } }
  else if (i <  9961472) { s = gB; d = gBb; i -= 4194304; }
  else if (i < 15728640) { s = uB; d = uBb; i -= 9961472; }
  else if (i < 21495808) { s = dA; d = dAb; i -= 15728640; }
  else if (i < 21512192) { s = gC; d = gCb; i -= 21495808; }
  else if (i < 21528576) { s = uC; d = uCb; i -= 21512192; }
  else return;
  float4 v = *(const float4*)(s + i);
  bf16x4 o;
  o[0] = (short)f2bf(v.x); o[1] = (short)f2bf(v.y);
  o[2] = (short)f2bf(v.z); o[3] = (short)f2bf(v.w);
  *(bf16x4*)(d + i) = o;
}

// Stage 1 (MFMA): h1 = A[e] @ x^T (K=2048), h2 = h1 @ C^T-rows (K=128) -> Hg/Hu bf16
__global__ __launch_bounds__(256) void k_stage1(
    const float* __restrict__ x, const int* __restrict__ tok,
    const short* __restrict__ gAb, const short* __restrict__ uAb,
    const short* __restrict__ gCb, const short* __restrict__ uCb,
    const int* __restrict__ off,
    short* __restrict__ Hgb, short* __restrict__ Hub)
{
  const int s0 = blockIdx.x * TILE_;
  if (s0 >= off[E_]) return;
  const int e = tile_expert(s0, off);
  const short* A = (blockIdx.y ? uAb : gAb) + (size_t)e * R_ * DH_;
  const short* C = blockIdx.y ? uCb : gCb;
  short* H = blockIdx.y ? Hub : Hgb;

  __shared__ short h1s[32][136];

  const int tid = threadIdx.x;
  const int lane = tid & 63, wv = tid >> 6;
  const int col = lane & 15, quad = lane >> 4;

  const float* xr[2];
#pragma unroll
  for (int m = 0; m < 2; m++) {
    int t = tok[s0 + m * 16 + col];
    xr[m] = (t >= 0) ? x + (size_t)t * DH_ + quad * 8 : nullptr;
  }
  const short* Ab0 = A + (size_t)(wv * 32 + col) * DH_ + quad * 8;
  const short* Ab1 = Ab0 + (size_t)16 * DH_;

  f32x4 acc[2][2] = {};
  for (int k0 = 0; k0 < DH_; k0 += 32) {
    bf16x8 a[2];
#pragma unroll
    for (int m = 0; m < 2; m++) {
      if (xr[m]) {
        float4 v0 = *(const float4*)(xr[m] + k0);
        float4 v1 = *(const float4*)(xr[m] + k0 + 4);
        a[m] = cvt8(v0, v1);
      } else {
        a[m] = (bf16x8){0, 0, 0, 0, 0, 0, 0, 0};
      }
    }
    bf16x8 b0 = *(const bf16x8*)(Ab0 + k0);
    bf16x8 b1 = *(const bf16x8*)(Ab1 + k0);
#pragma unroll
    for (int m = 0; m < 2; m++) {
      acc[m][0] = __builtin_amdgcn_mfma_f32_16x16x32_bf16(a[m], b0, acc[m][0], 0, 0, 0);
      acc[m][1] = __builtin_amdgcn_mfma_f32_16x16x32_bf16(a[m], b1, acc[m][1], 0, 0, 0);
    }
  }
  // h1 (C/D layout) -> LDS bf16 [token][r]
#pragma unroll
  for (int m = 0; m < 2; m++)
#pragma unroll
    for (int nl = 0; nl < 2; nl++)
#pragma unroll
      for (int r = 0; r < 4; r++)
        h1s[m * 16 + quad * 4 + r][(wv * 2 + nl) * 16 + col] = (short)f2bf(acc[m][nl][r]);
  __syncthreads();

  // C-apply: h2[t][s] = sum_r h1[t][r] * C[s][r]
  f32x4 acc2[2][2] = {};
#pragma unroll
  for (int kk = 0; kk < 4; kk++) {
    bf16x8 a0 = *(const bf16x8*)&h1s[col][kk * 32 + quad * 8];
    bf16x8 a1 = *(const bf16x8*)&h1s[16 + col][kk * 32 + quad * 8];
#pragma unroll
    for (int nl = 0; nl < 2; nl++) {
      bf16x8 b = *(const bf16x8*)(C + (size_t)((wv * 2 + nl) * 16 + col) * R_ + kk * 32 + quad * 8);
      acc2[0][nl] = __builtin_amdgcn_mfma_f32_16x16x32_bf16(a0, b, acc2[0][nl], 0, 0, 0);
      acc2[1][nl] = __builtin_amdgcn_mfma_f32_16x16x32_bf16(a1, b, acc2[1][nl], 0, 0, 0);
    }
  }
#pragma unroll
  for (int m = 0; m < 2; m++)
#pragma unroll
    for (int nl = 0; nl < 2; nl++)
#pragma unroll
      for (int r = 0; r < 4; r++)
        H[(size_t)(s0 + m * 16 + quad * 4 + r) * R_ + (wv * 2 + nl) * 16 + col] =
            (short)f2bf(acc2[m][nl][r]);
}

// Stage 2 (MFMA): G = Hg@Bg^T, U = Hu@Bu^T, Z = silu(G)*U, Hd1 += Z@Ad^T
__global__ __launch_bounds__(256) void k_stage2(
    const short* __restrict__ Hgb, const short* __restrict__ Hub,
    const short* __restrict__ gBb, const short* __restrict__ uBb,
    const short* __restrict__ dAb,
    const int* __restrict__ off, float* __restrict__ Hd1)
{
  const int s0 = blockIdx.x * TILE_;
  if (s0 >= off[E_]) return;
  const int e = tile_expert(s0, off);
  const int i0 = blockIdx.y * 512;
  const short* Bg = gBb + (size_t)e * DI_ * R_;
  const short* Bu = uBb + (size_t)e * DI_ * R_;
  const short* Ad = dAb + (size_t)e * R_ * DI_;

  __shared__ short ZT[32][136];

  const int tid = threadIdx.x;
  const int lane = tid & 63, wv = tid >> 6;
  const int col = lane & 15, quad = lane >> 4;

  // register-resident Hg/Hu A-fragments for both token halves, all K slices
  bf16x8 hg[2][4], hu[2][4];
#pragma unroll
  for (int m = 0; m < 2; m++)
#pragma unroll
    for (int kk = 0; kk < 4; kk++) {
      size_t o = (size_t)(s0 + m * 16 + col) * R_ + kk * 32 + quad * 8;
      hg[m][kk] = *(const bf16x8*)(Hgb + o);
      hu[m][kk] = *(const bf16x8*)(Hub + o);
    }

  f32x4 dacc[2][2] = {};

  for (int sc = 0; sc < 4; sc++) {
    const int ib = i0 + sc * 128;
    f32x4 gacc[2][2] = {}, uacc[2][2] = {};
#pragma unroll
    for (int kk = 0; kk < 4; kk++) {
#pragma unroll
      for (int nl = 0; nl < 2; nl++) {
        size_t bo = (size_t)(ib + (wv * 2 + nl) * 16 + col) * R_ + kk * 32 + quad * 8;
        bf16x8 bg = *(const bf16x8*)(Bg + bo);
        bf16x8 bu = *(const bf16x8*)(Bu + bo);
#pragma unroll
        for (int m = 0; m < 2; m++) {
          gacc[m][nl] = __builtin_amdgcn_mfma_f32_16x16x32_bf16(hg[m][kk], bg, gacc[m][nl], 0, 0, 0);
          uacc[m][nl] = __builtin_amdgcn_mfma_f32_16x16x32_bf16(hu[m][kk], bu, uacc[m][nl], 0, 0, 0);
        }
      }
    }
    __syncthreads();   // previous sub-chunk's ZT reads complete
    // Z = silu(G)*U -> ZT [token][di_local], bf16
#pragma unroll
    for (int m = 0; m < 2; m++)
#pragma unroll
      for (int nl = 0; nl < 2; nl++)
#pragma unroll
        for (int r = 0; r < 4; r++) {
          float g = gacc[m][nl][r];
          float z = (g / (1.0f + __expf(-g))) * uacc[m][nl][r];
          ZT[m * 16 + quad * 4 + r][(wv * 2 + nl) * 16 + col] = (short)f2bf(z);
        }
    __syncthreads();   // ZT ready
    // Hd1 partial: D[token][r] += Z[token][i] * Ad[r][i]
#pragma unroll
    for (int kk2 = 0; kk2 < 4; kk2++) {
      bf16x8 za0 = *(const bf16x8*)&ZT[col][kk2 * 32 + quad * 8];
      bf16x8 za1 = *(const bf16x8*)&ZT[16 + col][kk2 * 32 + quad * 8];
#pragma unroll
      for (int nl = 0; nl < 2; nl++) {
        bf16x8 ba = *(const bf16x8*)(Ad + (size_t)((wv * 2 + nl) * 16 + col) * DI_ +
                                     ib + kk2 * 32 + quad * 8);
        dacc[0][nl] = __builtin_amdgcn_mfma_f32_16x16x32_bf16(za0, ba, dacc[0][nl], 0, 0, 0);
        dacc[1][nl] = __builtin_amdgcn_mfma_f32_16x16x32_bf16(za1, ba, dacc[1][nl], 0, 0, 0);
      }
    }
  }
#pragma unroll
  for (int m = 0; m < 2; m++)
#pragma unroll
    for (int nl = 0; nl < 2; nl++)
#pragma unroll
      for (int r = 0; r < 4; r++)
        atomicAdd(&Hd1[(size_t)(s0 + m * 16 + quad * 4 + r) * R_ + (wv * 2 + nl) * 16 + col],
                  dacc[m][nl][r]);
}

// Hd2 = Cd @ Hd1 (fp32, unchanged from round 1)
__global__ __launch_bounds__(256) void k_applyCd(
    const float* __restrict__ Hd1, const float* __restrict__ dC,
    const int* __restrict__ off, float* __restrict__ Hd2)
{
  const int s0 = blockIdx.x * TILE_;
  if (s0 >= off[E_]) return;
  __shared__ float h1s[TILE_][132];
  __shared__ float CT[32][132];
  const int tid = threadIdx.x;
  const int lg = tid >> 3, lq = (tid & 7) * 16;
#pragma unroll
  for (int q = 0; q < 4; q++) {
    float4 v = *(const float4*)(Hd1 + (size_t)(s0 + lg) * R_ + lq + q * 4);
    *(float4*)&h1s[lg][lq + q * 4] = v;
  }
  const int gb = (tid >> 5) * 4, sb = (tid & 31) * 4;
  const int ls = tid >> 1, lrh = (tid & 1) * 16;
  float acc[4][4] = {};
  for (int rc = 0; rc < 4; rc++) {
    __syncthreads();
#pragma unroll
    for (int q = 0; q < 4; q++) {
      float4 v = *(const float4*)(dC + ls * R_ + rc * 32 + lrh + q * 4);
      CT[lrh + q * 4 + 0][ls] = v.x; CT[lrh + q * 4 + 1][ls] = v.y;
      CT[lrh + q * 4 + 2][ls] = v.z; CT[lrh + q * 4 + 3][ls] = v.w;
    }
    __syncthreads();
#pragma unroll 8
    for (int r = 0; r < 32; r++) {
      float4 cv = *(const float4*)&CT[r][sb];
      const float* cp = (const float*)&cv;
      float hv[4];
#pragma unroll
      for (int gi = 0; gi < 4; gi++) hv[gi] = h1s[gb + gi][rc * 32 + r];
#pragma unroll
      for (int gi = 0; gi < 4; gi++)
#pragma unroll
        for (int si = 0; si < 4; si++)
          acc[gi][si] += hv[gi] * cp[si];
    }
  }
#pragma unroll
  for (int gi = 0; gi < 4; gi++) {
    float4 o;
    o.x = acc[gi][0]; o.y = acc[gi][1]; o.z = acc[gi][2]; o.w = acc[gi][3];
    *(float4*)&Hd2[(size_t)(s0 + gb + gi) * R_ + sb] = o;
  }
}

// Stage 3 (fp32, unchanged): out[t, d] = Hd2[g,:] @ Bd[e,d,:] + bias[e,d]
__global__ __launch_bounds__(256) void k_stage3(
    const float* __restrict__ Hd2, const float* __restrict__ dBw,
    const float* __restrict__ dbias,
    const int* __restrict__ off, const int* __restrict__ tok,
    float* __restrict__ out)
{
  const int s0 = blockIdx.x * TILE_;
  if (s0 >= off[E_]) return;
  const int e = tile_expert(s0, off);
  const int d0 = blockIdx.y * 64;
  const float* Bd = dBw + (size_t)e * DH_ * R_;

  __shared__ float HdT[128][TILE_];
  __shared__ float BdT[128][68];

  const int tid = threadIdx.x;
  {
    const int lg = tid >> 3, lq = (tid & 7) * 16;
    const float* hp = Hd2 + (size_t)(s0 + lg) * R_ + lq;
#pragma unroll
    for (int q = 0; q < 4; q++) {
      float4 v = *(const float4*)(hp + q * 4);
      HdT[lq + q * 4 + 0][lg] = v.x; HdT[lq + q * 4 + 1][lg] = v.y;
      HdT[lq + q * 4 + 2][lg] = v.z; HdT[lq + q * 4 + 3][lg] = v.w;
    }
    const int ld = tid >> 2, lq2 = (tid & 3) * 32;
    const float* bp = Bd + (size_t)(d0 + ld) * R_ + lq2;
#pragma unroll
    for (int q = 0; q < 8; q++) {
      float4 v = *(const float4*)(bp + q * 4);
      BdT[lq2 + q * 4 + 0][ld] = v.x; BdT[lq2 + q * 4 + 1][ld] = v.y;
      BdT[lq2 + q * 4 + 2][ld] = v.z; BdT[lq2 + q * 4 + 3][ld] = v.w;
    }
  }
  __syncthreads();
  const int g2 = (tid & 15) * 2;
  const int d4 = (tid >> 4) * 4;
  float acc[2][4] = {};
#pragma unroll 8
  for (int k = 0; k < 128; k++) {
    float2 hv = *(const float2*)&HdT[k][g2];
    float4 bv = *(const float4*)&BdT[k][d4];
    const float* bp = (const float*)&bv;
#pragma unroll
    for (int di = 0; di < 4; di++) {
      acc[0][di] += hv.x * bp[di];
      acc[1][di] += hv.y * bp[di];
    }
  }
  float4 bias4 = *(const float4*)(dbias + (size_t)e * DH_ + d0 + d4);
  const float* bb = (const float*)&bias4;
#pragma unroll
  for (int gi = 0; gi < 2; gi++) {
    int t = tok[s0 + g2 + gi];
    if (t >= 0) {
      float4 o;
      o.x = acc[gi][0] + bb[0]; o.y = acc[gi][1] + bb[1];
      o.z = acc[gi][2] + bb[2]; o.w = acc[gi][3] + bb[3];
      *(float4*)&out[(size_t)t * DH_ + d0 + d4] = o;
    }
  }
}

extern "C" void kernel_launch(void* const* d_in, const int* in_sizes, int n_in,
                              void* d_out, int out_size, void* d_ws, size_t ws_size,
                              hipStream_t stream)
{
  (void)in_sizes; (void)n_in; (void)out_size; (void)ws_size;
  const float* x     = (const float*)d_in[0];
  const int*   idx   = (const int*)d_in[1];
  const float* gA    = (const float*)d_in[2];
  const float* gC    = (const float*)d_in[3];
  const float* gBw   = (const float*)d_in[4];
  const float* uA    = (const float*)d_in[5];
  const float* uC    = (const float*)d_in[6];
  const float* uBw   = (const float*)d_in[7];
  const float* dA    = (const float*)d_in[8];
  const float* dC    = (const float*)d_in[9];
  const float* dBw   = (const float*)d_in[10];
  const float* dbias = (const float*)d_in[11];
  float* out = (float*)d_out;

  char* ws = (char*)d_ws;
  int* cnt = (int*)ws;              // 8
  int* cur = cnt + 8;               // 8
  int* off = cnt + 16;              // 9
  int* tok = (int*)(ws + 512);      // 4352 ints
  float* Hd1 = (float*)(ws + 32768);           // 4352*128 f32
  float* Hd2 = (float*)(ws + 2260992);         // 4352*128 f32
  short* Hgb = (short*)(ws + 4489216);         // 4352*128 bf16
  short* Hub = (short*)(ws + 5603328);
  short* gAb = (short*)(ws + 6717440);         // 8*128*2048
  short* uAb = (short*)(ws + 10911744);
  short* gBb = (short*)(ws + 15106048);        // 8*5632*128
  short* uBb = (short*)(ws + 26640384);
  short* dAb = (short*)(ws + 38174720);        // 8*128*5632
  short* gCb = (short*)(ws + 49709056);        // 128*128
  short* uCb = (short*)(ws + 49741824);        // ends ~49.8 MB

  hipMemsetAsync(d_ws, 0, 128, stream);
  hipMemsetAsync(tok, 0xFF, TPMAX_ * sizeof(int), stream);
  hipMemsetAsync(Hd1, 0, (size_t)TPMAX_ * R_ * sizeof(float), stream);

  k_cvt    <<<dim3(21024), 256, 0, stream>>>(gA, uA, gBw, uBw, dA, gC, uC,
                                             gAb, uAb, gBb, uBb, dAb, gCb, uCb);
  k_count  <<<dim3(T_ / 256), 256, 0, stream>>>(idx, cnt);
  k_offsets<<<1, 64, 0, stream>>>(cnt, off, cur);
  k_scatter<<<dim3(T_ / 256), 256, 0, stream>>>(idx, cur, tok);
  k_stage1 <<<dim3(NT_, 2), 256, 0, stream>>>(x, tok, gAb, uAb, gCb, uCb, off, Hgb, Hub);
  k_stage2 <<<dim3(NT_, 11), 256, 0, stream>>>(Hgb, Hub, gBb, uBb, dAb, off, Hd1);
  k_applyCd<<<dim3(NT_), 256, 0, stream>>>(Hd1, dC, off, Hd2);
  k_stage3 <<<dim3(NT_, 32), 256, 0, stream>>>(Hd2, dBw, dbias, off, tok, out);
}

// Round 3
// 388.823 us; speedup vs baseline: 2.5035x; 1.1437x over previous
//
#include <hip/hip_runtime.h>
#include <hip/hip_bf16.h>

#define E_  8
#define T_  4096
#define DH_ 2048
#define DI_ 5632
#define R_  128
#define TILE_ 32
#define NT_ 136                 // T/32 + E  (worst-case padded tiles)
#define TPMAX_ (NT_*TILE_)      // 4352

typedef short bf16x8 __attribute__((ext_vector_type(8)));
typedef short bf16x4 __attribute__((ext_vector_type(4)));
typedef float f32x4 __attribute__((ext_vector_type(4)));

#define MFMA(a, b, c) __builtin_amdgcn_mfma_f32_16x16x32_bf16((a), (b), (c), 0, 0, 0)

__device__ __forceinline__ unsigned short f2bf(float f) {
  union { float f; unsigned u; } v; v.f = f;
  return (unsigned short)((v.u + 0x7fffu + ((v.u >> 16) & 1u)) >> 16);
}

__device__ __forceinline__ bf16x8 cvt8(float4 a, float4 b) {
  bf16x8 o;
  o[0] = (short)f2bf(a.x); o[1] = (short)f2bf(a.y);
  o[2] = (short)f2bf(a.z); o[3] = (short)f2bf(a.w);
  o[4] = (short)f2bf(b.x); o[5] = (short)f2bf(b.y);
  o[6] = (short)f2bf(b.z); o[7] = (short)f2bf(b.w);
  return o;
}

__device__ __forceinline__ int tile_expert(int s0, const int* off) {
  int e = 0;
#pragma unroll
  for (int q = 1; q < E_; q++) if (s0 >= off[q]) e = q;
  return e;
}

__global__ void k_count(const int* __restrict__ idx, int* __restrict__ cnt) {
  int t = blockIdx.x * 256 + threadIdx.x;
  if (t < T_) atomicAdd(&cnt[idx[t]], 1);
}

__global__ void k_offsets(const int* __restrict__ cnt, int* __restrict__ off,
                          int* __restrict__ cur) {
  if (threadIdx.x == 0) {
    int a = 0;
    for (int e = 0; e < E_; e++) {
      off[e] = a; cur[e] = a;
      a += ((cnt[e] + TILE_ - 1) / TILE_) * TILE_;
    }
    off[E_] = a;
  }
}

__global__ void k_scatter(const int* __restrict__ idx, int* __restrict__ cur,
                          int* __restrict__ tok) {
  int t = blockIdx.x * 256 + threadIdx.x;
  if (t < T_) {
    int p = atomicAdd(&cur[idx[t]], 1);
    tok[p] = t;
  }
}

// Convert all weights fp32 -> bf16 (layouts preserved)
__global__ __launch_bounds__(256) void k_cvt(
    const float* __restrict__ gA, const float* __restrict__ uA,
    const float* __restrict__ gB, const float* __restrict__ uB,
    const float* __restrict__ dA, const float* __restrict__ dB,
    const float* __restrict__ gC, const float* __restrict__ uC,
    const float* __restrict__ dC,
    short* __restrict__ gAb, short* __restrict__ uAb,
    short* __restrict__ gBb, short* __restrict__ uBb,
    short* __restrict__ dAb, short* __restrict__ dBb,
    short* __restrict__ gCb, short* __restrict__ uCb,
    short* __restrict__ dCb)
{
  long i = (long)(blockIdx.x * 256 + threadIdx.x) * 4;
  const float* s; short* d;
  if      (i <  4194304) { if (i < 2097152) { s = gA; d = gAb; } else { s = uA; d = uAb; i -= 2097152; } }
  else if (i <  9961472) { s = gB; d = gBb; i -= 4194304; }
  else if (i < 15728640) { s = uB; d = uBb; i -= 9961472; }
  else if (i < 21495808) { s = dA; d = dAb; i -= 15728640; }
  else if (i < 23592960) { s = dB; d = dBb; i -= 21495808; }
  else if (i < 23609344) { s = gC; d = gCb; i -= 23592960; }
  else if (i < 23625728) { s = uC; d = uCb; i -= 23609344; }
  else if (i < 23642112) { s = dC; d = dCb; i -= 23625728; }
  else return;
  float4 v = *(const float4*)(s + i);
  bf16x4 o;
  o[0] = (short)f2bf(v.x); o[1] = (short)f2bf(v.y);
  o[2] = (short)f2bf(v.z); o[3] = (short)f2bf(v.w);
  *(bf16x4*)(d + i) = o;
}

// Gather x rows into tile order, fp32 -> bf16 (zeros for pad rows)
__global__ __launch_bounds__(256) void k_gather(
    const float* __restrict__ x, const int* __restrict__ tok,
    short* __restrict__ Xb)
{
  const int p = blockIdx.x;
  const int t = tok[p];
  const int c = threadIdx.x * 8;
  bf16x8 o;
  if (t >= 0) {
    float4 v0 = *(const float4*)(x + (size_t)t * DH_ + c);
    float4 v1 = *(const float4*)(x + (size_t)t * DH_ + c + 4);
    o = cvt8(v0, v1);
  } else {
    o = (bf16x8){0, 0, 0, 0, 0, 0, 0, 0};
  }
  *(bf16x8*)(Xb + (size_t)p * DH_ + c) = o;
}

// Stage 1 (K-split): Hp[y][kc] partial = A[e][:, chunk] @ Xb[:, chunk]^T
__global__ __launch_bounds__(256) void k_stage1(
    const short* __restrict__ Xb,
    const short* __restrict__ gAb, const short* __restrict__ uAb,
    const int* __restrict__ off, float* __restrict__ Hp)
{
  const int s0 = blockIdx.x * TILE_;
  if (s0 >= off[E_]) return;
  const int e = tile_expert(s0, off);
  const int y = blockIdx.y, kc = blockIdx.z;
  const short* A = (y ? uAb : gAb) + (size_t)e * R_ * DH_ + kc * 512;

  const int tid = threadIdx.x;
  const int lane = tid & 63, wv = tid >> 6;
  const int col = lane & 15, quad = lane >> 4;

  const short* x0 = Xb + (size_t)(s0 + col) * DH_ + kc * 512 + quad * 8;
  const short* x1 = x0 + (size_t)16 * DH_;
  const short* Ab0 = A + (size_t)(wv * 32 + col) * DH_ + quad * 8;
  const short* Ab1 = Ab0 + (size_t)16 * DH_;

  f32x4 acc[2][2] = {};
#pragma unroll 4
  for (int k0 = 0; k0 < 512; k0 += 32) {
    bf16x8 a0 = *(const bf16x8*)(x0 + k0);
    bf16x8 a1 = *(const bf16x8*)(x1 + k0);
    bf16x8 b0 = *(const bf16x8*)(Ab0 + k0);
    bf16x8 b1 = *(const bf16x8*)(Ab1 + k0);
    acc[0][0] = MFMA(a0, b0, acc[0][0]);
    acc[0][1] = MFMA(a0, b1, acc[0][1]);
    acc[1][0] = MFMA(a1, b0, acc[1][0]);
    acc[1][1] = MFMA(a1, b1, acc[1][1]);
  }
  float* O = Hp + (size_t)(y * 4 + kc) * TPMAX_ * R_;
#pragma unroll
  for (int m = 0; m < 2; m++)
#pragma unroll
    for (int nl = 0; nl < 2; nl++)
#pragma unroll
      for (int r = 0; r < 4; r++)
        O[(size_t)(s0 + m * 16 + quad * 4 + r) * R_ + (wv * 2 + nl) * 16 + col] =
            acc[m][nl][r];
}

// Stage 1b: sum K-partials, apply C via MFMA, write Hg/Hu bf16
__global__ __launch_bounds__(256) void k_stage1b(
    const float* __restrict__ Hp,
    const short* __restrict__ gCb, const short* __restrict__ uCb,
    const int* __restrict__ off,
    short* __restrict__ Hgb, short* __restrict__ Hub)
{
  const int s0 = blockIdx.x * TILE_;
  if (s0 >= off[E_]) return;
  const int y = blockIdx.y;
  const short* C = y ? uCb : gCb;
  short* H = y ? Hub : Hgb;

  __shared__ short h1s[32][136];
  const int tid = threadIdx.x;
  {
    const int lg = tid >> 3, lq = (tid & 7) * 16;
    const float* base = Hp + ((size_t)y * 4 * TPMAX_ + s0 + lg) * R_ + lq;
    float s[16] = {};
#pragma unroll
    for (int kc = 0; kc < 4; kc++) {
      const float* p = base + (size_t)kc * TPMAX_ * R_;
#pragma unroll
      for (int q = 0; q < 4; q++) {
        float4 v = *(const float4*)(p + q * 4);
        s[q * 4 + 0] += v.x; s[q * 4 + 1] += v.y;
        s[q * 4 + 2] += v.z; s[q * 4 + 3] += v.w;
      }
    }
#pragma unroll
    for (int j = 0; j < 16; j++) h1s[lg][lq + j] = (short)f2bf(s[j]);
  }
  __syncthreads();

  const int lane = tid & 63, wv = tid >> 6;
  const int col = lane & 15, quad = lane >> 4;
  f32x4 acc2[2][2] = {};
#pragma unroll
  for (int kk = 0; kk < 4; kk++) {
    bf16x8 a0 = *(const bf16x8*)&h1s[col][kk * 32 + quad * 8];
    bf16x8 a1 = *(const bf16x8*)&h1s[16 + col][kk * 32 + quad * 8];
#pragma unroll
    for (int nl = 0; nl < 2; nl++) {
      bf16x8 b = *(const bf16x8*)(C + (size_t)((wv * 2 + nl) * 16 + col) * R_ +
                                  kk * 32 + quad * 8);
      acc2[0][nl] = MFMA(a0, b, acc2[0][nl]);
      acc2[1][nl] = MFMA(a1, b, acc2[1][nl]);
    }
  }
#pragma unroll
  for (int m = 0; m < 2; m++)
#pragma unroll
    for (int nl = 0; nl < 2; nl++)
#pragma unroll
      for (int r = 0; r < 4; r++)
        H[(size_t)(s0 + m * 16 + quad * 4 + r) * R_ + (wv * 2 + nl) * 16 + col] =
            (short)f2bf(acc2[m][nl][r]);
}

// Stage 2 (MFMA): G = Hg@Bg^T, U = Hu@Bu^T, Z = silu(G)*U, Hd1 += Z@Ad^T
__global__ __launch_bounds__(256) void k_stage2(
    const short* __restrict__ Hgb, const short* __restrict__ Hub,
    const short* __restrict__ gBb, const short* __restrict__ uBb,
    const short* __restrict__ dAb,
    const int* __restrict__ off, float* __restrict__ Hd1)
{
  const int s0 = blockIdx.x * TILE_;
  if (s0 >= off[E_]) return;
  const int e = tile_expert(s0, off);
  const int i0 = blockIdx.y * 512;
  const short* Bg = gBb + (size_t)e * DI_ * R_;
  const short* Bu = uBb + (size_t)e * DI_ * R_;
  const short* Ad = dAb + (size_t)e * R_ * DI_;

  __shared__ short ZT[32][136];

  const int tid = threadIdx.x;
  const int lane = tid & 63, wv = tid >> 6;
  const int col = lane & 15, quad = lane >> 4;

  bf16x8 hg[2][4], hu[2][4];
#pragma unroll
  for (int m = 0; m < 2; m++)
#pragma unroll
    for (int kk = 0; kk < 4; kk++) {
      size_t o = (size_t)(s0 + m * 16 + col) * R_ + kk * 32 + quad * 8;
      hg[m][kk] = *(const bf16x8*)(Hgb + o);
      hu[m][kk] = *(const bf16x8*)(Hub + o);
    }

  f32x4 dacc[2][2] = {};

  for (int sc = 0; sc < 4; sc++) {
    const int ib = i0 + sc * 128;
    f32x4 gacc[2][2] = {}, uacc[2][2] = {};
#pragma unroll
    for (int kk = 0; kk < 4; kk++) {
#pragma unroll
      for (int nl = 0; nl < 2; nl++) {
        size_t bo = (size_t)(ib + (wv * 2 + nl) * 16 + col) * R_ + kk * 32 + quad * 8;
        bf16x8 bg = *(const bf16x8*)(Bg + bo);
        bf16x8 bu = *(const bf16x8*)(Bu + bo);
#pragma unroll
        for (int m = 0; m < 2; m++) {
          gacc[m][nl] = MFMA(hg[m][kk], bg, gacc[m][nl]);
          uacc[m][nl] = MFMA(hu[m][kk], bu, uacc[m][nl]);
        }
      }
    }
    __syncthreads();
#pragma unroll
    for (int m = 0; m < 2; m++)
#pragma unroll
      for (int nl = 0; nl < 2; nl++)
#pragma unroll
        for (int r = 0; r < 4; r++) {
          float g = gacc[m][nl][r];
          float z = (g / (1.0f + __expf(-g))) * uacc[m][nl][r];
          ZT[m * 16 + quad * 4 + r][(wv * 2 + nl) * 16 + col] = (short)f2bf(z);
        }
    __syncthreads();
#pragma unroll
    for (int kk2 = 0; kk2 < 4; kk2++) {
      bf16x8 za0 = *(const bf16x8*)&ZT[col][kk2 * 32 + quad * 8];
      bf16x8 za1 = *(const bf16x8*)&ZT[16 + col][kk2 * 32 + quad * 8];
#pragma unroll
      for (int nl = 0; nl < 2; nl++) {
        bf16x8 ba = *(const bf16x8*)(Ad + (size_t)((wv * 2 + nl) * 16 + col) * DI_ +
                                     ib + kk2 * 32 + quad * 8);
        dacc[0][nl] = MFMA(za0, ba, dacc[0][nl]);
        dacc[1][nl] = MFMA(za1, ba, dacc[1][nl]);
      }
    }
  }
#pragma unroll
  for (int m = 0; m < 2; m++)
#pragma unroll
    for (int nl = 0; nl < 2; nl++)
#pragma unroll
      for (int r = 0; r < 4; r++)
        atomicAdd(&Hd1[(size_t)(s0 + m * 16 + quad * 4 + r) * R_ + (wv * 2 + nl) * 16 + col],
                  dacc[m][nl][r]);
}

// Stage 3 (MFMA): h2 = (Hd1 @ dC^T); out = h2 @ dB^T + bias, scatter to tokens
__global__ __launch_bounds__(256) void k_stage3(
    const float* __restrict__ Hd1, const short* __restrict__ dCb,
    const short* __restrict__ dBb, const float* __restrict__ dbias,
    const int* __restrict__ off, const int* __restrict__ tok,
    float* __restrict__ out)
{
  const int s0 = blockIdx.x * TILE_;
  if (s0 >= off[E_]) return;
  const int e = tile_expert(s0, off);
  const int d0 = blockIdx.y * 128;

  __shared__ short h2s[32][136];
  const int tid = threadIdx.x;
  const int lane = tid & 63, wv = tid >> 6;
  const int col = lane & 15, quad = lane >> 4;

  // phase 1: h2[t][s] = sum_r Hd1[t][r] * dC[s][r]   (redundant across d0-blocks; tiny)
  f32x4 acc2[2][2] = {};
#pragma unroll
  for (int kk = 0; kk < 4; kk++) {
    bf16x8 a[2];
#pragma unroll
    for (int m = 0; m < 2; m++) {
      const float* hp = Hd1 + (size_t)(s0 + m * 16 + col) * R_ + kk * 32 + quad * 8;
      float4 v0 = *(const float4*)hp;
      float4 v1 = *(const float4*)(hp + 4);
      a[m] = cvt8(v0, v1);
    }
#pragma unroll
    for (int nl = 0; nl < 2; nl++) {
      bf16x8 b = *(const bf16x8*)(dCb + (size_t)((wv * 2 + nl) * 16 + col) * R_ +
                                  kk * 32 + quad * 8);
      acc2[0][nl] = MFMA(a[0], b, acc2[0][nl]);
      acc2[1][nl] = MFMA(a[1], b, acc2[1][nl]);
    }
  }
#pragma unroll
  for (int m = 0; m < 2; m++)
#pragma unroll
    for (int nl = 0; nl < 2; nl++)
#pragma unroll
      for (int r = 0; r < 4; r++)
        h2s[m * 16 + quad * 4 + r][(wv * 2 + nl) * 16 + col] = (short)f2bf(acc2[m][nl][r]);
  __syncthreads();

  // phase 2: out[t][d] = sum_s h2[t][s] * dB[d][s]
  f32x4 acc3[2][2] = {};
#pragma unroll
  for (int kk = 0; kk < 4; kk++) {
    bf16x8 a0 = *(const bf16x8*)&h2s[col][kk * 32 + quad * 8];
    bf16x8 a1 = *(const bf16x8*)&h2s[16 + col][kk * 32 + quad * 8];
#pragma unroll
    for (int nl = 0; nl < 2; nl++) {
      bf16x8 b = *(const bf16x8*)(dBb + (size_t)e * DH_ * R_ +
                                  (size_t)(d0 + (wv * 2 + nl) * 16 + col) * R_ +
                                  kk * 32 + quad * 8);
      acc3[0][nl] = MFMA(a0, b, acc3[0][nl]);
      acc3[1][nl] = MFMA(a1, b, acc3[1][nl]);
    }
  }
  float bias[2];
#pragma unroll
  for (int nl = 0; nl < 2; nl++)
    bias[nl] = dbias[(size_t)e * DH_ + d0 + (wv * 2 + nl) * 16 + col];
#pragma unroll
  for (int m = 0; m < 2; m++)
#pragma unroll
    for (int r = 0; r < 4; r++) {
      int t = tok[s0 + m * 16 + quad * 4 + r];
      if (t < 0) continue;
#pragma unroll
      for (int nl = 0; nl < 2; nl++) {
        int d = d0 + (wv * 2 + nl) * 16 + col;
        out[(size_t)t * DH_ + d] = acc3[m][nl][r] + bias[nl];
      }
    }
}

extern "C" void kernel_launch(void* const* d_in, const int* in_sizes, int n_in,
                              void* d_out, int out_size, void* d_ws, size_t ws_size,
                              hipStream_t stream)
{
  (void)in_sizes; (void)n_in; (void)out_size; (void)ws_size;
  const float* x     = (const float*)d_in[0];
  const int*   idx   = (const int*)d_in[1];
  const float* gA    = (const float*)d_in[2];
  const float* gC    = (const float*)d_in[3];
  const float* gBw   = (const float*)d_in[4];
  const float* uA    = (const float*)d_in[5];
  const float* uC    = (const float*)d_in[6];
  const float* uBw   = (const float*)d_in[7];
  const float* dA    = (const float*)d_in[8];
  const float* dC    = (const float*)d_in[9];
  const float* dBw   = (const float*)d_in[10];
  const float* dbias = (const float*)d_in[11];
  float* out = (float*)d_out;

  char* ws = (char*)d_ws;
  int* cnt = (int*)ws;                          // 8
  int* cur = cnt + 8;                           // 8
  int* off = cnt + 16;                          // 9
  int* tok = (int*)(ws + 512);                  // 4352 ints
  float* Hd1 = (float*)(ws + 32768);            // TPMAX*128 f32      -> 2260992
  float* Hp  = (float*)(ws + 2260992);          // 2*4*TPMAX*128 f32  -> 20086784
  short* Xb  = (short*)(ws + 20086784);         // TPMAX*2048 bf16    -> 37912576
  short* Hgb = (short*)(ws + 37912576);         // TPMAX*128 bf16     -> 39026688
  short* Hub = (short*)(ws + 39026688);         //                    -> 40140800
  short* gAb = (short*)(ws + 40140800);         // 8*128*2048         -> 44335104
  short* uAb = (short*)(ws + 44335104);         //                    -> 48529408
  short* gBb = (short*)(ws + 48529408);         // 8*5632*128         -> 60063744
  short* uBb = (short*)(ws + 60063744);         //                    -> 71598080
  short* dAb = (short*)(ws + 71598080);         // 8*128*5632         -> 83132416
  short* dBb = (short*)(ws + 83132416);         // 8*2048*128         -> 87326720
  short* gCb = (short*)(ws + 87326720);         // 128*128            -> 87359488
  short* uCb = (short*)(ws + 87359488);         //                    -> 87392256
  short* dCb = (short*)(ws + 87392256);         //                    -> 87425024

  hipMemsetAsync(d_ws, 0, 128, stream);
  hipMemsetAsync(tok, 0xFF, TPMAX_ * sizeof(int), stream);
  hipMemsetAsync(Hd1, 0, (size_t)TPMAX_ * R_ * sizeof(float), stream);

  k_cvt    <<<dim3(23088), 256, 0, stream>>>(gA, uA, gBw, uBw, dA, dBw, gC, uC, dC,
                                             gAb, uAb, gBb, uBb, dAb, dBb, gCb, uCb, dCb);
  k_count  <<<dim3(T_ / 256), 256, 0, stream>>>(idx, cnt);
  k_offsets<<<1, 64, 0, stream>>>(cnt, off, cur);
  k_scatter<<<dim3(T_ / 256), 256, 0, stream>>>(idx, cur, tok);
  k_gather <<<dim3(TPMAX_), 256, 0, stream>>>(x, tok, Xb);
  k_stage1 <<<dim3(NT_, 2, 4), 256, 0, stream>>>(Xb, gAb, uAb, off, Hp);
  k_stage1b<<<dim3(NT_, 2), 256, 0, stream>>>(Hp, gCb, uCb, off, Hgb, Hub);
  k_stage2 <<<dim3(NT_, 11), 256, 0, stream>>>(Hgb, Hub, gBb, uBb, dAb, off, Hd1);
  k_stage3 <<<dim3(NT_, 16), 256, 0, stream>>>(Hd1, dCb, dBb, dbias, off, tok, out);
}

// Round 4
// 334.684 us; speedup vs baseline: 2.9084x; 1.1618x over previous
//
#include <hip/hip_runtime.h>
#include <hip/hip_bf16.h>

#define E_  8
#define T_  4096
#define DH_ 2048
#define DI_ 5632
#define R_  128
#define TILE_ 64
#define NT_ 72                  // T/64 + E  (worst-case padded tiles)
#define TPMAX_ (NT_*TILE_)      // 4608

typedef short bf16x8 __attribute__((ext_vector_type(8)));
typedef short bf16x4 __attribute__((ext_vector_type(4)));
typedef float f32x4 __attribute__((ext_vector_type(4)));

#define MFMA(a, b, c) __builtin_amdgcn_mfma_f32_16x16x32_bf16((a), (b), (c), 0, 0, 0)

__device__ __forceinline__ unsigned short f2bf(float f) {
  union { float f; unsigned u; } v; v.f = f;
  return (unsigned short)((v.u + 0x7fffu + ((v.u >> 16) & 1u)) >> 16);
}

__device__ __forceinline__ bf16x8 cvt8(float4 a, float4 b) {
  bf16x8 o;
  o[0] = (short)f2bf(a.x); o[1] = (short)f2bf(a.y);
  o[2] = (short)f2bf(a.z); o[3] = (short)f2bf(a.w);
  o[4] = (short)f2bf(b.x); o[5] = (short)f2bf(b.y);
  o[6] = (short)f2bf(b.z); o[7] = (short)f2bf(b.w);
  return o;
}

__device__ __forceinline__ int tile_expert(int s0, const int* off) {
  int e = 0;
#pragma unroll
  for (int q = 1; q < E_; q++) if (s0 >= off[q]) e = q;
  return e;
}

// count + offsets (pad 64) + scatter in one block
__global__ __launch_bounds__(1024) void k_route(
    const int* __restrict__ idx, int* __restrict__ off, int* __restrict__ tok)
{
  __shared__ int cnt[E_], cur[E_], offs[E_ + 1];
  const int tid = threadIdx.x;
  if (tid < E_) cnt[tid] = 0;
  __syncthreads();
  for (int t = tid; t < T_; t += 1024) atomicAdd(&cnt[idx[t]], 1);
  __syncthreads();
  if (tid == 0) {
    int a = 0;
    for (int e = 0; e < E_; e++) {
      offs[e] = a; cur[e] = a;
      a += ((cnt[e] + TILE_ - 1) / TILE_) * TILE_;
    }
    offs[E_] = a;
  }
  __syncthreads();
  if (tid <= E_) off[tid] = offs[tid];
  for (int t = tid; t < T_; t += 1024) {
    int p = atomicAdd(&cur[idx[t]], 1);
    tok[p] = t;
  }
}

// Convert all weights fp32 -> bf16 (layouts preserved)
__global__ __launch_bounds__(256) void k_cvt(
    const float* __restrict__ gA, const float* __restrict__ uA,
    const float* __restrict__ gB, const float* __restrict__ uB,
    const float* __restrict__ dA, const float* __restrict__ dB,
    const float* __restrict__ gC, const float* __restrict__ uC,
    const float* __restrict__ dC,
    short* __restrict__ gAb, short* __restrict__ uAb,
    short* __restrict__ gBb, short* __restrict__ uBb,
    short* __restrict__ dAb, short* __restrict__ dBb,
    short* __restrict__ gCb, short* __restrict__ uCb,
    short* __restrict__ dCb)
{
  long i = (long)(blockIdx.x * 256 + threadIdx.x) * 4;
  const float* s; short* d;
  if      (i <  4194304) { if (i < 2097152) { s = gA; d = gAb; } else { s = uA; d = uAb; i -= 2097152; } }
  else if (i <  9961472) { s = gB; d = gBb; i -= 4194304; }
  else if (i < 15728640) { s = uB; d = uBb; i -= 9961472; }
  else if (i < 21495808) { s = dA; d = dAb; i -= 15728640; }
  else if (i < 23592960) { s = dB; d = dBb; i -= 21495808; }
  else if (i < 23609344) { s = gC; d = gCb; i -= 23592960; }
  else if (i < 23625728) { s = uC; d = uCb; i -= 23609344; }
  else if (i < 23642112) { s = dC; d = dCb; i -= 23625728; }
  else return;
  float4 v = *(const float4*)(s + i);
  bf16x4 o;
  o[0] = (short)f2bf(v.x); o[1] = (short)f2bf(v.y);
  o[2] = (short)f2bf(v.z); o[3] = (short)f2bf(v.w);
  *(bf16x4*)(d + i) = o;
}

// Gather x rows into tile order, fp32 -> bf16 (zeros for pad rows)
__global__ __launch_bounds__(256) void k_gather(
    const float* __restrict__ x, const int* __restrict__ tok,
    short* __restrict__ Xb)
{
  const int p = blockIdx.x;
  const int t = tok[p];
  const int c = threadIdx.x * 8;
  bf16x8 o;
  if (t >= 0) {
    float4 v0 = *(const float4*)(x + (size_t)t * DH_ + c);
    float4 v1 = *(const float4*)(x + (size_t)t * DH_ + c + 4);
    o = cvt8(v0, v1);
  } else {
    o = (bf16x8){0, 0, 0, 0, 0, 0, 0, 0};
  }
  *(bf16x8*)(Xb + (size_t)p * DH_ + c) = o;
}

// Stage 1 (K-split, 64-token tiles): Hp[y][kc] partial = Xb_tile @ A[e]-chunk^T
__global__ __launch_bounds__(256) void k_stage1(
    const short* __restrict__ Xb,
    const short* __restrict__ gAb, const short* __restrict__ uAb,
    const int* __restrict__ off, float* __restrict__ Hp)
{
  const int s0 = blockIdx.x * TILE_;
  if (s0 >= off[E_]) return;
  const int e = tile_expert(s0, off);
  const int y = blockIdx.y, kc = blockIdx.z;
  const short* A = (y ? uAb : gAb) + (size_t)e * R_ * DH_ + kc * 512;

  const int tid = threadIdx.x;
  const int lane = tid & 63, wv = tid >> 6;
  const int col = lane & 15, quad = lane >> 4;

  const short* xb = Xb + (size_t)(s0 + col) * DH_ + kc * 512 + quad * 8;
  const short* ab = A + (size_t)(wv * 32 + col) * DH_ + quad * 8;

  f32x4 acc[4][2] = {};
#pragma unroll 4
  for (int k0 = 0; k0 < 512; k0 += 32) {
    bf16x8 b0 = *(const bf16x8*)(ab + k0);
    bf16x8 b1 = *(const bf16x8*)(ab + (size_t)16 * DH_ + k0);
#pragma unroll
    for (int m = 0; m < 4; m++) {
      bf16x8 a = *(const bf16x8*)(xb + (size_t)m * 16 * DH_ + k0);
      acc[m][0] = MFMA(a, b0, acc[m][0]);
      acc[m][1] = MFMA(a, b1, acc[m][1]);
    }
  }
  float* O = Hp + (size_t)(y * 4 + kc) * TPMAX_ * R_;
#pragma unroll
  for (int m = 0; m < 4; m++)
#pragma unroll
    for (int nl = 0; nl < 2; nl++)
#pragma unroll
      for (int r = 0; r < 4; r++)
        O[(size_t)(s0 + m * 16 + quad * 4 + r) * R_ + (wv * 2 + nl) * 16 + col] =
            acc[m][nl][r];
}

// Stage 1b: sum K-partials, apply C via MFMA, write Hg/Hu bf16
__global__ __launch_bounds__(256) void k_stage1b(
    const float* __restrict__ Hp,
    const short* __restrict__ gCb, const short* __restrict__ uCb,
    const int* __restrict__ off,
    short* __restrict__ Hgb, short* __restrict__ Hub)
{
  const int s0 = blockIdx.x * TILE_;
  if (s0 >= off[E_]) return;
  const int y = blockIdx.y;
  const short* C = y ? uCb : gCb;
  short* H = y ? Hub : Hgb;

  __shared__ short h1s[64][136];
  const int tid = threadIdx.x;
  {
    const int lg = tid >> 2, lq = (tid & 3) * 32;
    const float* base = Hp + ((size_t)y * 4 * TPMAX_ + s0 + lg) * R_ + lq;
    float s[32] = {};
#pragma unroll
    for (int kc = 0; kc < 4; kc++) {
      const float* p = base + (size_t)kc * TPMAX_ * R_;
#pragma unroll
      for (int q = 0; q < 8; q++) {
        float4 v = *(const float4*)(p + q * 4);
        s[q * 4 + 0] += v.x; s[q * 4 + 1] += v.y;
        s[q * 4 + 2] += v.z; s[q * 4 + 3] += v.w;
      }
    }
#pragma unroll
    for (int j = 0; j < 32; j++) h1s[lg][lq + j] = (short)f2bf(s[j]);
  }
  __syncthreads();

  const int lane = tid & 63, wv = tid >> 6;
  const int col = lane & 15, quad = lane >> 4;
  f32x4 acc2[4][2] = {};
#pragma unroll
  for (int kk = 0; kk < 4; kk++) {
    bf16x8 b[2];
#pragma unroll
    for (int nl = 0; nl < 2; nl++)
      b[nl] = *(const bf16x8*)(C + (size_t)((wv * 2 + nl) * 16 + col) * R_ +
                               kk * 32 + quad * 8);
#pragma unroll
    for (int m = 0; m < 4; m++) {
      bf16x8 a = *(const bf16x8*)&h1s[m * 16 + col][kk * 32 + quad * 8];
      acc2[m][0] = MFMA(a, b[0], acc2[m][0]);
      acc2[m][1] = MFMA(a, b[1], acc2[m][1]);
    }
  }
#pragma unroll
  for (int m = 0; m < 4; m++)
#pragma unroll
    for (int nl = 0; nl < 2; nl++)
#pragma unroll
      for (int r = 0; r < 4; r++)
        H[(size_t)(s0 + m * 16 + quad * 4 + r) * R_ + (wv * 2 + nl) * 16 + col] =
            (short)f2bf(acc2[m][nl][r]);
}

// Stage 2 (64-token tiles): G/U B-proj, silu-mul, down-A partial accumulate
__global__ __launch_bounds__(256) void k_stage2(
    const short* __restrict__ Hgb, const short* __restrict__ Hub,
    const short* __restrict__ gBb, const short* __restrict__ uBb,
    const short* __restrict__ dAb,
    const int* __restrict__ off, float* __restrict__ Hd1)
{
  const int s0 = blockIdx.x * TILE_;
  if (s0 >= off[E_]) return;
  const int e = tile_expert(s0, off);
  const int i0 = blockIdx.y * 512;
  const short* Bg = gBb + (size_t)e * DI_ * R_;
  const short* Bu = uBb + (size_t)e * DI_ * R_;
  const short* Ad = dAb + (size_t)e * R_ * DI_;

  __shared__ short hgs[64][136];
  __shared__ short hus[64][136];
  __shared__ short ZT[64][136];

  const int tid = threadIdx.x;
  const int lane = tid & 63, wv = tid >> 6;
  const int col = lane & 15, quad = lane >> 4;

  // stage Hg/Hu tile into LDS (4 threads/row, 32 shorts each)
  {
    const int row = tid >> 2, seg = (tid & 3) * 32;
    const short* pg = Hgb + (size_t)(s0 + row) * R_ + seg;
    const short* pu = Hub + (size_t)(s0 + row) * R_ + seg;
#pragma unroll
    for (int q = 0; q < 4; q++) {
      *(bf16x8*)&hgs[row][seg + q * 8] = *(const bf16x8*)(pg + q * 8);
      *(bf16x8*)&hus[row][seg + q * 8] = *(const bf16x8*)(pu + q * 8);
    }
  }
  __syncthreads();

  f32x4 dacc[4][2] = {};

  for (int sc = 0; sc < 4; sc++) {
    const int ib = i0 + sc * 128;
    f32x4 gacc[4][2] = {}, uacc[4][2] = {};
#pragma unroll
    for (int kk = 0; kk < 4; kk++) {
      bf16x8 bg[2], bu[2];
#pragma unroll
      for (int nl = 0; nl < 2; nl++) {
        size_t bo = (size_t)(ib + (wv * 2 + nl) * 16 + col) * R_ + kk * 32 + quad * 8;
        bg[nl] = *(const bf16x8*)(Bg + bo);
        bu[nl] = *(const bf16x8*)(Bu + bo);
      }
#pragma unroll
      for (int m = 0; m < 4; m++) {
        bf16x8 ag = *(const bf16x8*)&hgs[m * 16 + col][kk * 32 + quad * 8];
        bf16x8 au = *(const bf16x8*)&hus[m * 16 + col][kk * 32 + quad * 8];
#pragma unroll
        for (int nl = 0; nl < 2; nl++) {
          gacc[m][nl] = MFMA(ag, bg[nl], gacc[m][nl]);
          uacc[m][nl] = MFMA(au, bu[nl], uacc[m][nl]);
        }
      }
    }
    __syncthreads();   // previous sub-chunk's ZT reads complete
#pragma unroll
    for (int m = 0; m < 4; m++)
#pragma unroll
      for (int nl = 0; nl < 2; nl++)
#pragma unroll
        for (int r = 0; r < 4; r++) {
          float g = gacc[m][nl][r];
          float z = (g / (1.0f + __expf(-g))) * uacc[m][nl][r];
          ZT[m * 16 + quad * 4 + r][(wv * 2 + nl) * 16 + col] = (short)f2bf(z);
        }
    __syncthreads();   // ZT ready
#pragma unroll
    for (int kk2 = 0; kk2 < 4; kk2++) {
      bf16x8 ba[2];
#pragma unroll
      for (int nl = 0; nl < 2; nl++)
        ba[nl] = *(const bf16x8*)(Ad + (size_t)((wv * 2 + nl) * 16 + col) * DI_ +
                                  ib + kk2 * 32 + quad * 8);
#pragma unroll
      for (int m = 0; m < 4; m++) {
        bf16x8 za = *(const bf16x8*)&ZT[m * 16 + col][kk2 * 32 + quad * 8];
        dacc[m][0] = MFMA(za, ba[0], dacc[m][0]);
        dacc[m][1] = MFMA(za, ba[1], dacc[m][1]);
      }
    }
  }
#pragma unroll
  for (int m = 0; m < 4; m++)
#pragma unroll
    for (int nl = 0; nl < 2; nl++)
#pragma unroll
      for (int r = 0; r < 4; r++)
        atomicAdd(&Hd1[(size_t)(s0 + m * 16 + quad * 4 + r) * R_ + (wv * 2 + nl) * 16 + col],
                  dacc[m][nl][r]);
}

// Stage 3: h2 = Hd1 @ dC^T (redundant per d-chunk, tiny); out = h2 @ dB^T + bias
__global__ __launch_bounds__(256) void k_stage3(
    const float* __restrict__ Hd1, const short* __restrict__ dCb,
    const short* __restrict__ dBb, const float* __restrict__ dbias,
    const int* __restrict__ off, const int* __restrict__ tok,
    float* __restrict__ out)
{
  const int s0 = blockIdx.x * TILE_;
  if (s0 >= off[E_]) return;
  const int e = tile_expert(s0, off);
  const int d0 = blockIdx.y * 128;

  __shared__ short h2s[64][136];
  const int tid = threadIdx.x;
  const int lane = tid & 63, wv = tid >> 6;
  const int col = lane & 15, quad = lane >> 4;

  f32x4 acc2[4][2] = {};
#pragma unroll
  for (int kk = 0; kk < 4; kk++) {
    bf16x8 b[2];
#pragma unroll
    for (int nl = 0; nl < 2; nl++)
      b[nl] = *(const bf16x8*)(dCb + (size_t)((wv * 2 + nl) * 16 + col) * R_ +
                               kk * 32 + quad * 8);
#pragma unroll
    for (int m = 0; m < 4; m++) {
      const float* hp = Hd1 + (size_t)(s0 + m * 16 + col) * R_ + kk * 32 + quad * 8;
      float4 v0 = *(const float4*)hp;
      float4 v1 = *(const float4*)(hp + 4);
      bf16x8 a = cvt8(v0, v1);
      acc2[m][0] = MFMA(a, b[0], acc2[m][0]);
      acc2[m][1] = MFMA(a, b[1], acc2[m][1]);
    }
  }
#pragma unroll
  for (int m = 0; m < 4; m++)
#pragma unroll
    for (int nl = 0; nl < 2; nl++)
#pragma unroll
      for (int r = 0; r < 4; r++)
        h2s[m * 16 + quad * 4 + r][(wv * 2 + nl) * 16 + col] = (short)f2bf(acc2[m][nl][r]);
  __syncthreads();

  f32x4 acc3[4][2] = {};
#pragma unroll
  for (int kk = 0; kk < 4; kk++) {
    bf16x8 b[2];
#pragma unroll
    for (int nl = 0; nl < 2; nl++)
      b[nl] = *(const bf16x8*)(dBb + (size_t)e * DH_ * R_ +
                               (size_t)(d0 + (wv * 2 + nl) * 16 + col) * R_ +
                               kk * 32 + quad * 8);
#pragma unroll
    for (int m = 0; m < 4; m++) {
      bf16x8 a = *(const bf16x8*)&h2s[m * 16 + col][kk * 32 + quad * 8];
      acc3[m][0] = MFMA(a, b[0], acc3[m][0]);
      acc3[m][1] = MFMA(a, b[1], acc3[m][1]);
    }
  }
  float bias[2];
#pragma unroll
  for (int nl = 0; nl < 2; nl++)
    bias[nl] = dbias[(size_t)e * DH_ + d0 + (wv * 2 + nl) * 16 + col];
#pragma unroll
  for (int m = 0; m < 4; m++)
#pragma unroll
    for (int r = 0; r < 4; r++) {
      int t = tok[s0 + m * 16 + quad * 4 + r];
      if (t < 0) continue;
#pragma unroll
      for (int nl = 0; nl < 2; nl++) {
        int d = d0 + (wv * 2 + nl) * 16 + col;
        out[(size_t)t * DH_ + d] = acc3[m][nl][r] + bias[nl];
      }
    }
}

extern "C" void kernel_launch(void* const* d_in, const int* in_sizes, int n_in,
                              void* d_out, int out_size, void* d_ws, size_t ws_size,
                              hipStream_t stream)
{
  (void)in_sizes; (void)n_in; (void)out_size; (void)ws_size;
  const float* x     = (const float*)d_in[0];
  const int*   idx   = (const int*)d_in[1];
  const float* gA    = (const float*)d_in[2];
  const float* gC    = (const float*)d_in[3];
  const float* gBw   = (const float*)d_in[4];
  const float* uA    = (const float*)d_in[5];
  const float* uC    = (const float*)d_in[6];
  const float* uBw   = (const float*)d_in[7];
  const float* dA    = (const float*)d_in[8];
  const float* dC    = (const float*)d_in[9];
  const float* dBw   = (const float*)d_in[10];
  const float* dbias = (const float*)d_in[11];
  float* out = (float*)d_out;

  char* ws = (char*)d_ws;
  int* off = (int*)ws;                          // 9 ints
  int* tok = (int*)(ws + 512);                  // 4608 ints       -> 18944
  float* Hd1 = (float*)(ws + 32768);            // 4608*128 f32    -> 2392064
  float* Hp  = (float*)(ws + 2392064);          // 8*4608*128 f32  -> 21266432
  short* Xb  = (short*)(ws + 21266432);         // 4608*2048 bf16  -> 40140800
  short* Hgb = (short*)(ws + 40140800);         // 4608*128 bf16   -> 41320448
  short* Hub = (short*)(ws + 41320448);         //                 -> 42500096
  short* gAb = (short*)(ws + 42500096);         // 8*128*2048      -> 46694400
  short* uAb = (short*)(ws + 46694400);         //                 -> 50888704
  short* gBb = (short*)(ws + 50888704);         // 8*5632*128      -> 62423040
  short* uBb = (short*)(ws + 62423040);         //                 -> 73957376
  short* dAb = (short*)(ws + 73957376);         // 8*128*5632      -> 85491712
  short* dBb = (short*)(ws + 85491712);         // 8*2048*128      -> 89686016
  short* gCb = (short*)(ws + 89686016);         // 128*128         -> 89718784
  short* uCb = (short*)(ws + 89718784);         //                 -> 89751552
  short* dCb = (short*)(ws + 89751552);         //                 -> 89784320

  hipMemsetAsync(tok, 0xFF, TPMAX_ * sizeof(int), stream);
  hipMemsetAsync(Hd1, 0, (size_t)TPMAX_ * R_ * sizeof(float), stream);

  k_cvt    <<<dim3(23088), 256, 0, stream>>>(gA, uA, gBw, uBw, dA, dBw, gC, uC, dC,
                                             gAb, uAb, gBb, uBb, dAb, dBb, gCb, uCb, dCb);
  k_route  <<<1, 1024, 0, stream>>>(idx, off, tok);
  k_gather <<<dim3(TPMAX_), 256, 0, stream>>>(x, tok, Xb);
  k_stage1 <<<dim3(NT_, 2, 4), 256, 0, stream>>>(Xb, gAb, uAb, off, Hp);
  k_stage1b<<<dim3(NT_, 2), 256, 0, stream>>>(Hp, gCb, uCb, off, Hgb, Hub);
  k_stage2 <<<dim3(NT_, 11), 256, 0, stream>>>(Hgb, Hub, gBb, uBb, dAb, off, Hd1);
  k_stage3 <<<dim3(NT_, 16), 256, 0, stream>>>(Hd1, dCb, dBb, dbias, off, tok, out);
}